// Round 7
// baseline (1999.682 us; speedup 1.0000x reference)
//
#include <hip/hip_runtime.h>
#include <hip/hip_bf16.h>

#define HD 512      // d_model
#define NST 64      // d_state
#define NLAY 6
#define LSEQ 784
#define BB 64       // batch
#define NKA 848     // reversed+padded kernel array length (u16)
#define TOFF 800    // KA[t] = K[TOFF - t]; t in [17,800] real, else 0
#define LPADROWS 800  // padded L (25 tiles of 32); pad rows killed by zero-K
#define KSTR 850    // u16 stride between shifted K copies
#define CHK2 5      // 32-row l-tiles per conv block; 25 = 5*5
#define NCH 5       // chunks
#define UTS2 9      // UT row stride in dwords (8 j-pairs + 1 pad)

typedef unsigned short u16;
typedef short s8v __attribute__((ext_vector_type(8)));   // 8 bf16 (4 VGPR)
typedef float f16v __attribute__((ext_vector_type(16))); // 32x32 MFMA acc
typedef u16  u4h __attribute__((ext_vector_type(4)));    // ushort4 (8B)
typedef u16  u8h __attribute__((ext_vector_type(8)));    // ushort8 (16B)

// fp32 -> bf16 bits, round-to-nearest-even
__device__ __forceinline__ unsigned f2b(float f)
{
    unsigned u = __builtin_bit_cast(unsigned, f);
    return (u + 0x7FFFu + ((u >> 16) & 1u)) >> 16;
}
__device__ __forceinline__ float b2f16(u16 v)
{
    unsigned u = ((unsigned)v) << 16;
    return __builtin_bit_cast(float, u);
}
// pack 2 fp32 -> 2 bf16 (RNE), lo|hi<<16 — single HW instruction on gfx950
__device__ __forceinline__ unsigned pkbf(float lo, float hi)
{
    unsigned r;
    asm("v_cvt_pk_bf16_f32 %0, %1, %2" : "=v"(r) : "v"(lo), "v"(hi));
    return r;
}

// ---------------------------------------------------------------------------
// Per (layer,h,n): lambda = exp(dt*A), dtA, 2*Cd. Layout [i][h][n].
// ---------------------------------------------------------------------------
__global__ void precompute_k(const float* __restrict__ log_dt,
                             const float* __restrict__ log_A_real,
                             const float* __restrict__ A_imag,
                             const float* __restrict__ C_re,
                             const float* __restrict__ C_im,
                             float* __restrict__ lamr, float* __restrict__ lami,
                             float* __restrict__ dtr,  float* __restrict__ dti,
                             float* __restrict__ c2r,  float* __restrict__ c2i)
{
    int t = blockIdx.x * 256 + threadIdx.x;
    if (t >= NLAY * HD * NST) return;
    int ih = t >> 6;                       // i*HD + h
    float dt  = expf(log_dt[ih]);
    float are = -expf(log_A_real[t]);
    float aim = A_imag[t];
    float dr = are * dt, di = aim * dt;
    float er = expf(dr);
    float sn, cs; __sincosf(di, &sn, &cs);
    float lr = er * cs, li = er * sn;      // lambda
    float e1r = lr - 1.0f, e1i = li;
    float den = are * are + aim * aim;
    float qr = (e1r * are + e1i * aim) / den;
    float qi = (e1i * are - e1r * aim) / den;
    float crv = C_re[t], civ = C_im[t];
    lamr[t] = lr; lami[t] = li; dtr[t] = dr; dti[t] = di;
    c2r[t] = 2.0f * (crv * qr - civ * qi);
    c2i[t] = 2.0f * (crv * qi + civ * qr);
}

// ---------------------------------------------------------------------------
// Build KA[i][h][t] (bf16): reversed, zero-padded conv kernel.
// 4-way n-chain interleave for ILP (bit-exact: each acc[k] still sums its
// terms in ascending-n order).
// ---------------------------------------------------------------------------
__global__ void kq_k(const float* __restrict__ lamr, const float* __restrict__ lami,
                     const float* __restrict__ dtr,  const float* __restrict__ dti,
                     const float* __restrict__ c2r,  const float* __restrict__ c2i,
                     u16* __restrict__ KA)
{
    int t = blockIdx.x * 256 + threadIdx.x;   // < 6*512*49
    int dc = t % 49;
    int ih = t / 49;                          // i*HD + h
    int d0 = dc * 16;
    float acc[16];
#pragma unroll
    for (int k = 0; k < 16; k++) acc[k] = 0.f;
    int base = ih * 64;
    for (int n = 0; n < 64; n += 4) {
        float lr[4], li[4], cr[4], ci[4], pr[4], pi[4];
#pragma unroll
        for (int j = 0; j < 4; j++) {
            int q = base + n + j;
            lr[j] = lamr[q]; li[j] = lami[q];
            float dr = dtr[q], di = dti[q];
            cr[j] = c2r[q]; ci[j] = c2i[q];
            float e = __expf(dr * (float)d0);
            float sn, cs; __sincosf(di * (float)d0, &sn, &cs);
            pr[j] = e * cs; pi[j] = e * sn;   // lam^d0
        }
#pragma unroll
        for (int k = 0; k < 16; k++) {
#pragma unroll
            for (int j = 0; j < 4; j++) {
                acc[k] = fmaf(cr[j], pr[j], fmaf(-ci[j], pi[j], acc[k]));
                float nr = pr[j] * lr[j] - pi[j] * li[j];
                pi[j] = fmaf(pr[j], li[j], pi[j] * lr[j]);
                pr[j] = nr;
            }
        }
    }
    u16* kap = KA + (size_t)ih * NKA;
#pragma unroll
    for (int k = 0; k < 16; k++)
        kap[TOFF - (d0 + k)] = (u16)f2b(acc[k]);
    if (dc == 0)  for (int z = TOFF + 1; z < NKA; z++) kap[z] = 0;
    if (dc == 48) for (int z = 0; z < TOFF - 783; z++) kap[z] = 0;
}

// ---------------------------------------------------------------------------
// Transpose x[b][l] -> xT[l][b] (200 KB, L2-resident; cost ~2 us)
// ---------------------------------------------------------------------------
__global__ void xt_k(const float* __restrict__ x, float* __restrict__ xT)
{
    int t = blockIdx.x * 256 + threadIdx.x;   // < 784*64
    int l = t >> 6, b = t & 63;
    xT[t] = x[b * LSEQ + l];
}

// ---------------------------------------------------------------------------
// Encoder: thread = (l, h, b-oct).  Extended to LPADROWS: pad rows get ZEROS
// (so staging never ingests uninitialized ws memory / NaNs).
// ---------------------------------------------------------------------------
__global__ void encoder_k(const float* __restrict__ xT, const float* __restrict__ ew,
                          const float* __restrict__ eb, u16* __restrict__ Vb)
{
    int g = blockIdx.x * 256 + threadIdx.x;   // < 800*512*8
    int bo = g & 7;
    int h  = (g >> 3) & 511;
    int l  = g >> 12;
    uint4* dst = (uint4*)&Vb[((size_t)l * HD + h) * BB + 8 * bo];
    if (l >= LSEQ) { *dst = (uint4){0, 0, 0, 0}; return; }
    const float4* xp = (const float4*)&xT[l * BB + 8 * bo];
    float4 a0 = xp[0], a1 = xp[1];
    float w = ew[h], bb = eb[h];
    unsigned p0 = f2b(fmaf(a0.x, w, bb)) | (f2b(fmaf(a0.y, w, bb)) << 16);
    unsigned p1 = f2b(fmaf(a0.z, w, bb)) | (f2b(fmaf(a0.w, w, bb)) << 16);
    unsigned p2 = f2b(fmaf(a1.x, w, bb)) | (f2b(fmaf(a1.y, w, bb)) << 16);
    unsigned p3 = f2b(fmaf(a1.z, w, bb)) | (f2b(fmaf(a1.w, w, bb)) << 16);
    *dst = (uint4){p0, p1, p2, p3};
}

// ---------------------------------------------------------------------------
// Per-(l,b) LayerNorm stats of pre-LN stream P: M[l][b] = {mu, rs}.
// Pad rows (l >= LSEQ) get identity stats {0,1} so fused-LN stays finite.
// ---------------------------------------------------------------------------
__global__ __launch_bounds__(256)
void stats_k(const u16* __restrict__ P, float2* __restrict__ M)
{
    __shared__ float redS[32][65], redQ[32][65];
    const int thr = threadIdx.x;
    const size_t l = blockIdx.x;
    if (l >= LSEQ) {
        if (thr < BB) M[l * BB + thr] = make_float2(0.f, 1.f);
        return;
    }
    const int bo = thr & 7;           // b = 8*bo + i
    const int ho = thr >> 3;          // h = 16*ho + k
    const u16* sp = &P[(l * HD + (size_t)ho * 16) * BB + 8 * bo];
    float s[8] = {0, 0, 0, 0, 0, 0, 0, 0};
    float q[8] = {0, 0, 0, 0, 0, 0, 0, 0};
#pragma unroll
    for (int k = 0; k < 16; k++) {
        u8h r = *(const u8h*)(sp + (size_t)k * BB);
#pragma unroll
        for (int i = 0; i < 8; i++) {
            float x = b2f16(r[i]);
            s[i] += x;
            q[i] = fmaf(x, x, q[i]);
        }
    }
#pragma unroll
    for (int i = 0; i < 8; i++) { redS[ho][8 * bo + i] = s[i]; redQ[ho][8 * bo + i] = q[i]; }
    __syncthreads();
    if (thr < 64) {
        float ts = 0.f, tq = 0.f;
#pragma unroll
        for (int g = 0; g < 32; g++) { ts += redS[g][thr]; tq += redQ[g][thr]; }
        float mu = ts * (1.0f / HD);
        float rs = rsqrtf(tq * (1.0f / HD) - mu * mu + 1e-5f);
        M[l * BB + thr] = make_float2(mu, rs);
    }
}

// ---------------------------------------------------------------------------
// MFMA causal-Toeplitz conv + residual via 32x32x16 bf16 MFMA.
// FLN=1: previous layer's LN applied on the fly (M{mu,rs}, gp/bp per h).
// Dispatch: c-major reversed (LPT).  K=32 PER ITERATION: each barrier
// interval stages 32 j-rows (two 16-row sub-tiles A/B in separate LDS
// buffers) and issues up to 10 MFMAs.  Halves the barrier count (latency-
// bound iterations: ~560 cyc each regardless of work inside).  Loads are
// issued and consumed within the SAME iteration — no cross-barrier register
// liveness (the pattern rounds 3-5 proved the compiler rejects).
// Accumulation order per acc[lt] unchanged (sub A = old jt 2J before
// sub B = old jt 2J+1) -> bit-exact vs round-2 kernel.
// ---------------------------------------------------------------------------
template<int FLN>
__global__ __launch_bounds__(128, 4)
void conv_k(const u16* __restrict__ Vb, u16* __restrict__ V2,
            const u16* __restrict__ KA, const float* __restrict__ Dvec,
            const float2* __restrict__ M,
            const float* __restrict__ gp, const float* __restrict__ bp)
{
    __shared__ __align__(16) u16 KR[6816];                 // 8 shifted copies
    __shared__ __align__(16) unsigned UT[2][2][64 * UTS2]; // [J&1][sub]

    const int thr = threadIdx.x;
    const int bid = blockIdx.x;
    const int c   = NCH - 1 - (bid >> 9);    // 4,...,0 (LPT order)
    const int h   = bid & 511;
    const int w   = thr >> 6;                // b-half (n-tile)
    const int lane = thr & 63;
    const int n2 = lane & 31;
    const int qp = lane >> 5;
    const int JTN = 5 * c + 5;               // 32-row tiles

    const float gh = FLN ? gp[h] : 0.f;
    const float bh = FLN ? bp[h] : 0.f;

    const u16* kap = KA + (size_t)h * NKA;
    {
        int s = thr & 7, ch = thr >> 3;      // 16 chunks x 53 (covers 848)
        int i0 = ch * 53;
        int i1 = (i0 + 53 < NKA) ? (i0 + 53) : NKA;
        u16* kr = KR + KSTR * s + ((8 - s) & 7);
        for (int i = i0; i < i1; i++) kr[i] = kap[i];
    }

    const int jj = thr >> 4;
    const int bq = thr & 15;

    // load rows (j0+2jj, j0+2jj+1), cols 4bq..4bq+3 (+ LN stats)
    auto LOAD16 = [&](int j0, u4h& r0, u4h& r1,
                      float4& mA0, float4& mB0, float4& mA1, float4& mB1) {
        int j = j0 + 2 * jj;
        const u16* p = &Vb[((size_t)j * HD + h) * BB + 4 * bq];
        r0 = *(const u4h*)p;
        r1 = *(const u4h*)(p + (size_t)HD * BB);
        if (FLN) {
            const float4* m0p = (const float4*)&M[(size_t)j * BB + 4 * bq];
            const float4* m1p = (const float4*)&M[(size_t)(j + 1) * BB + 4 * bq];
            mA0 = m0p[0]; mB0 = m0p[1]; mA1 = m1p[0]; mB1 = m1p[1];
        }
    };
    // normalize (FLN) + pack + LDS write to buffer base `up`
    auto WRITE16 = [&](unsigned* up, u4h r0, u4h r1,
                       float4 mA0, float4 mB0, float4 mA1, float4 mB1) {
        if (FLN) {
            float A0[4] = {mA0.y * gh, mA0.w * gh, mB0.y * gh, mB0.w * gh};
            float C0[4] = {fmaf(-mA0.x, A0[0], bh), fmaf(-mA0.z, A0[1], bh),
                           fmaf(-mB0.x, A0[2], bh), fmaf(-mB0.z, A0[3], bh)};
            float A1[4] = {mA1.y * gh, mA1.w * gh, mB1.y * gh, mB1.w * gh};
            float C1[4] = {fmaf(-mA1.x, A1[0], bh), fmaf(-mA1.z, A1[1], bh),
                           fmaf(-mB1.x, A1[2], bh), fmaf(-mB1.z, A1[3], bh)};
#pragma unroll
            for (int i = 0; i < 4; i++) {
                float x0 = fmaf(b2f16(r0[i]), A0[i], C0[i]);
                float x1 = fmaf(b2f16(r1[i]), A1[i], C1[i]);
                up[(4 * bq + i) * UTS2 + jj] = pkbf(x0, x1);
            }
        } else {
#pragma unroll
            for (int i = 0; i < 4; i++)
                up[(4 * bq + i) * UTS2 + jj] = (unsigned)r0[i] | ((unsigned)r1[i] << 16);
        }
    };

    // prologue: stage tile J=0 (rows 0..31) into UT[0][0], UT[0][1]
    {
        u4h t0, t1; float4 a0, a1, a2, a3;
        LOAD16(0, t0, t1, a0, a1, a2, a3);
        WRITE16(&UT[0][0][0], t0, t1, a0, a1, a2, a3);
        LOAD16(16, t0, t1, a0, a1, a2, a3);
        WRITE16(&UT[0][1][0], t0, t1, a0, a1, a2, a3);
    }
    __syncthreads();

    f16v acc[CHK2];
#pragma unroll
    for (int i = 0; i < CHK2; i++)
#pragma unroll
        for (int r = 0; r < 16; r++) acc[i][r] = 0.f;

    const float dcoef = 1.0f + Dvec[h];

    const int s = lane & 7;
    const u16* krb = KR + KSTR * s + ((8 - s) & 7)
                     + (TOFF - 160 * c) + 8 * qp - n2;
    const int uoff = (32 * w + n2) * UTS2 + 4 * qp;
    const unsigned* bA0 = &UT[0][0][uoff];
    const unsigned* bB0 = &UT[0][1][uoff];
    const unsigned* bA1 = &UT[1][0][uoff];
    const unsigned* bB1 = &UT[1][1][uoff];

    for (int J = 0; J < JTN; ++J) {
        u4h ra0, ra1, rb0, rb1;
        float4 maA0, maB0, maA1, maB1, mbA0, mbB0, mbA1, mbB1;
        const bool more = (J + 1) < JTN;
        if (more) {
            LOAD16(32 * (J + 1),      ra0, ra1, maA0, maB0, maA1, maB1);
            LOAD16(32 * (J + 1) + 16, rb0, rb1, mbA0, mbB0, mbA1, mbB1);
        }

        const unsigned* bbA = (J & 1) ? bA1 : bA0;
        const unsigned* bbB = (J & 1) ? bB1 : bB0;
        union { unsigned u[4]; s8v v; } buA, buB;
        buA.u[0] = bbA[0]; buA.u[1] = bbA[1]; buA.u[2] = bbA[2]; buA.u[3] = bbA[3];
        buB.u[0] = bbB[0]; buB.u[1] = bbB[1]; buB.u[2] = bbB[2]; buB.u[3] = bbB[3];

        const u16* ap0 = krb + 32 * J;
#pragma unroll
        for (int lt = 0; lt < CHK2; ++lt) {
            const int lim = 10 * c + 2 * lt + 1;
            if (2 * J <= lim) {                       // sub A (old jt = 2J)
                s8v av = *(const s8v*)__builtin_assume_aligned(ap0 - 32 * lt, 16);
                acc[lt] = __builtin_amdgcn_mfma_f32_32x32x16_bf16(av, buA.v, acc[lt], 0, 0, 0);
            }
            if (2 * J + 1 <= lim) {                   // sub B (old jt = 2J+1)
                s8v av = *(const s8v*)__builtin_assume_aligned(ap0 + 16 - 32 * lt, 16);
                acc[lt] = __builtin_amdgcn_mfma_f32_32x32x16_bf16(av, buB.v, acc[lt], 0, 0, 0);
            }
        }
        if (more) {
            unsigned* upA = &UT[(J & 1) ^ 1][0][0];
            unsigned* upB = &UT[(J & 1) ^ 1][1][0];
            WRITE16(upA, ra0, ra1, maA0, maB0, maA1, maB1);
            WRITE16(upB, rb0, rb1, mbA0, mbB0, mbA1, mbB1);
        }
        __syncthreads();
    }

    // epilogue: V2 = bf16(y + (1+D)*u), u = fused-LN(P) when FLN
#pragma unroll
    for (int lt = 0; lt < CHK2; ++lt) {
        const int l0 = 32 * (5 * c + lt) + 4 * qp;
#pragma unroll
        for (int r = 0; r < 16; ++r) {
            int l = l0 + (r & 3) + 8 * (r >> 2);
            size_t a = ((size_t)l * HD + h) * BB + 32 * w + n2;
            float x = b2f16(Vb[a]);
            float u = x;
            if (FLN) {
                float2 m = M[(size_t)l * BB + 32 * w + n2];
                u = fmaf(x - m.x, m.y * gh, bh);
            }
            V2[a] = (u16)f2b(fmaf(dcoef, u, acc[lt][r]));
        }
    }
}

// ---------------------------------------------------------------------------
// Fused double-LN tail: u6 = LN5(P5) (per-(l,b) stats in M, per-h g5/b5),
// then final LN over h of u6, write bf16. In-place safe (block owns its l).
// ---------------------------------------------------------------------------
__global__ __launch_bounds__(512)
void lnT2_k(const u16* __restrict__ src, u16* __restrict__ dst,
            const float2* __restrict__ M,
            const float* __restrict__ g5p, const float* __restrict__ b5p,
            const float* __restrict__ gp, const float* __restrict__ bp)
{
    __shared__ float redS[64][65], redQ[64][65];
    __shared__ float mus[64], rss[64];
    __shared__ float gs[512], bs[512];
    const int thr = threadIdx.x;
    const int bo = thr & 7;           // b = 8*bo + i
    const int hg = thr >> 3;          // h = 8*hg + k
    const size_t l = blockIdx.x;
    gs[thr] = gp[thr]; bs[thr] = bp[thr];

    const float4* mp = (const float4*)&M[l * BB + 8 * bo];
    float4 m0 = mp[0], m1 = mp[1], m2 = mp[2], m3 = mp[3];
    float mu5[8] = {m0.x, m0.z, m1.x, m1.z, m2.x, m2.z, m3.x, m3.z};
    float rs5[8] = {m0.y, m0.w, m1.y, m1.w, m2.y, m2.w, m3.y, m3.w};

    const u16* sp = &src[(l * HD + (size_t)hg * 8) * BB + 8 * bo];
    float v[64];                       // v[k*8+i]
    float s[8] = {0, 0, 0, 0, 0, 0, 0, 0};
    float q[8] = {0, 0, 0, 0, 0, 0, 0, 0};
#pragma unroll
    for (int k = 0; k < 8; k++) {
        u8h r = *(const u8h*)(sp + (size_t)k * BB);
        float g5 = g5p[hg * 8 + k], b5 = b5p[hg * 8 + k];
#pragma unroll
        for (int i = 0; i < 8; i++) {
            float x = fmaf(b2f16(r[i]) - mu5[i], rs5[i] * g5, b5);
            v[k * 8 + i] = x;
            s[i] += x;
            q[i] = fmaf(x, x, q[i]);
        }
    }
#pragma unroll
    for (int i = 0; i < 8; i++) { redS[hg][8 * bo + i] = s[i]; redQ[hg][8 * bo + i] = q[i]; }
    __syncthreads();
    if (thr < 64) {
        float ts = 0.f, tq = 0.f;
#pragma unroll
        for (int g = 0; g < 64; g++) { ts += redS[g][thr]; tq += redQ[g][thr]; }
        float mu = ts * (1.0f / HD);
        mus[thr] = mu;
        rss[thr] = rsqrtf(tq * (1.0f / HD) - mu * mu + 1e-5f);
    }
    __syncthreads();
    float mu[8], rs[8];
#pragma unroll
    for (int i = 0; i < 8; i++) { mu[i] = mus[8 * bo + i]; rs[i] = rss[8 * bo + i]; }
    u16* dp = &dst[(l * HD + (size_t)hg * 8) * BB + 8 * bo];
#pragma unroll
    for (int k = 0; k < 8; k++) {
        float g = gs[hg * 8 + k], bb = bs[hg * 8 + k];
        u8h wv;
#pragma unroll
        for (int i = 0; i < 8; i++)
            wv[i] = (u16)f2b(fmaf((v[k * 8 + i] - mu[i]) * rs[i], g, bb));
        *(u8h*)(dp + (size_t)k * BB) = wv;
    }
}

// ---------------------------------------------------------------------------
// Mean-pool over l from bf16 Vb: PO[h*64+b] = mean_l Vb[l][h][b].
// ---------------------------------------------------------------------------
__global__ void pool_k(const u16* __restrict__ Vb, float* __restrict__ PO)
{
    __shared__ float red[4][64];
    int h = blockIdx.x;
    int b = threadIdx.x & 63;
    int lg = threadIdx.x >> 6;               // 0..3
    const u16* p = &Vb[(size_t)h * BB + b];
    float s = 0.f;
    for (int l = lg; l < LSEQ; l += 4) s += b2f16(p[(size_t)l * HD * BB]);
    red[lg][b] = s;
    __syncthreads();
    if (threadIdx.x < 64) {
        float t = red[0][b] + red[1][b] + red[2][b] + red[3][b];
        PO[h * BB + b] = t * (1.0f / LSEQ);
    }
}

// ---------------------------------------------------------------------------
// Decoder: out[b,c] = PO[:,b] . dec_w[:,c] + dec_b[c]
// ---------------------------------------------------------------------------
__global__ void dec_k(const float* __restrict__ PO, const float* __restrict__ w,
                      const float* __restrict__ bias, float* __restrict__ out)
{
    int t = blockIdx.x * 256 + threadIdx.x;
    if (t >= BB * 10) return;
    int cc = t % 10, b = t / 10;
    float acc = bias[cc];
    for (int hh = 0; hh < HD; hh++)
        acc = fmaf(PO[hh * BB + b], w[hh * 10 + cc], acc);
    out[t] = acc;
}

// ---------------------------------------------------------------------------
extern "C" void kernel_launch(void* const* d_in, const int* in_sizes, int n_in,
                              void* d_out, int out_size, void* d_ws, size_t ws_size,
                              hipStream_t stream)
{
    const float* x   = (const float*)d_in[0];
    const float* ew  = (const float*)d_in[1];
    const float* eb  = (const float*)d_in[2];
    const float* ldt = (const float*)d_in[3];
    const float* lar = (const float*)d_in[4];
    const float* aim = (const float*)d_in[5];
    const float* cre = (const float*)d_in[6];
    const float* cim = (const float*)d_in[7];
    const float* Dp  = (const float*)d_in[8];
    const float* lng = (const float*)d_in[9];
    const float* lnb = (const float*)d_in[10];
    const float* fng = (const float*)d_in[11];
    const float* fnb = (const float*)d_in[12];
    const float* dw  = (const float*)d_in[13];
    const float* db  = (const float*)d_in[14];
    float* out = (float*)d_out;

    const size_t SZB = (size_t)BB * LPADROWS * HD;   // 26,214,400 u16 slots
    const size_t PP  = (size_t)NLAY * HD * NST;      // 196,608
    u16*   Vb  = (u16*)d_ws;                // bf16 stream buffer A [l][h][b]
    u16*   V2  = Vb + SZB;                  // bf16 stream buffer B
    float* PAR = (float*)(V2 + SZB);
    float* lamr = PAR,        * lami = PAR + PP;
    float* dtr  = PAR + 2*PP, * dti  = PAR + 3*PP;
    float* c2r  = PAR + 4*PP, * c2i  = PAR + 5*PP;
    u16* KA = (u16*)(PAR + 6 * PP);                  // 6*512*848 u16
    float* PO = PAR + 6 * PP + (NLAY * HD * NKA) / 2;
    float* xT = PO + BB * HD;                        // 784*64 fp32
    // M (LN stats, 800*64 float2 = 400KB) aliases PAR: PAR only feeds kq_k,
    // which completes before the first stats_k writes M.
    float2* M = (float2*)PAR;

    precompute_k<<<(NLAY * HD * NST + 255) / 256, 256, 0, stream>>>(
        ldt, lar, aim, cre, cim, lamr, lami, dtr, dti, c2r, c2i);
    kq_k<<<(NLAY * HD * 49) / 256, 256, 0, stream>>>(
        lamr, lami, dtr, dti, c2r, c2i, KA);
    xt_k<<<(LSEQ * BB) / 256, 256, 0, stream>>>(x, xT);
    encoder_k<<<(LPADROWS * HD * 8) / 256, 256, 0, stream>>>(xT, ew, eb, Vb);

    // layer 0: raw input (no fused LN), P0 -> V2
    conv_k<0><<<512 * NCH, 128, 0, stream>>>(Vb, V2, KA, Dp, M, lng, lnb);
    stats_k<<<LPADROWS, 256, 0, stream>>>(V2, M);
    // layers 1..5: fuse LN of layer i-1 into staging/epilogue
    for (int i = 1; i < NLAY; i++) {
        const u16* srcb = (i & 1) ? V2 : Vb;
        u16*       dstb = (i & 1) ? Vb : V2;
        conv_k<1><<<512 * NCH, 128, 0, stream>>>(
            srcb, dstb, KA + (size_t)i * HD * NKA, Dp + i * HD,
            M, lng + (size_t)(i - 1) * HD, lnb + (size_t)(i - 1) * HD);
        stats_k<<<LPADROWS, 256, 0, stream>>>(dstb, M);
    }
    // P5 is in Vb; fused LN5 + final LN, in place
    lnT2_k<<<LSEQ, 512, 0, stream>>>(Vb, Vb, M, lng + 5 * HD, lnb + 5 * HD, fng, fnb);
    pool_k<<<HD, 256, 0, stream>>>(Vb, PO);
    dec_k<<<(BB * 10 + 255) / 256, 256, 0, stream>>>(PO, dw, db, out);
}

// Round 8
// 622.002 us; speedup vs baseline: 3.2149x; 3.2149x over previous
//
#include <hip/hip_runtime.h>
#include <hip/hip_bf16.h>

#define HD 512      // d_model
#define NST 64      // d_state
#define NLAY 6
#define LSEQ 784
#define BB 64       // batch
#define NKA 848     // reversed+padded kernel array length (u16)
#define TOFF 800    // KA[t] = K[TOFF - t]; t in [17,800] real, else 0
#define LPADROWS 800  // padded L (25 tiles of 32); pad rows killed by zero-K
#define KSTR 850    // u16 stride between shifted K copies
#define CHK2 5      // 32-row l-tiles per conv block; 25 = 5*5
#define NCH 5       // chunks
#define UTS2 9      // UT row stride in dwords (8 j-pairs + 1 pad)

typedef unsigned short u16;
typedef short s8v __attribute__((ext_vector_type(8)));   // 8 bf16 (4 VGPR)
typedef float f16v __attribute__((ext_vector_type(16))); // 32x32 MFMA acc
typedef u16  u4h __attribute__((ext_vector_type(4)));    // ushort4 (8B)
typedef u16  u8h __attribute__((ext_vector_type(8)));    // ushort8 (16B)

// fp32 -> bf16 bits, round-to-nearest-even
__device__ __forceinline__ unsigned f2b(float f)
{
    unsigned u = __builtin_bit_cast(unsigned, f);
    return (u + 0x7FFFu + ((u >> 16) & 1u)) >> 16;
}
__device__ __forceinline__ float b2f16(u16 v)
{
    unsigned u = ((unsigned)v) << 16;
    return __builtin_bit_cast(float, u);
}

// ---------------------------------------------------------------------------
// Per (layer,h,n): lambda = exp(dt*A), dtA, 2*Cd. Layout [i][h][n].
// ---------------------------------------------------------------------------
__global__ void precompute_k(const float* __restrict__ log_dt,
                             const float* __restrict__ log_A_real,
                             const float* __restrict__ A_imag,
                             const float* __restrict__ C_re,
                             const float* __restrict__ C_im,
                             float* __restrict__ lamr, float* __restrict__ lami,
                             float* __restrict__ dtr,  float* __restrict__ dti,
                             float* __restrict__ c2r,  float* __restrict__ c2i)
{
    int t = blockIdx.x * 256 + threadIdx.x;
    if (t >= NLAY * HD * NST) return;
    int ih = t >> 6;                       // i*HD + h
    float dt  = expf(log_dt[ih]);
    float are = -expf(log_A_real[t]);
    float aim = A_imag[t];
    float dr = are * dt, di = aim * dt;
    float er = expf(dr);
    float sn, cs; __sincosf(di, &sn, &cs);
    float lr = er * cs, li = er * sn;      // lambda
    float e1r = lr - 1.0f, e1i = li;
    float den = are * are + aim * aim;
    float qr = (e1r * are + e1i * aim) / den;
    float qi = (e1i * are - e1r * aim) / den;
    float crv = C_re[t], civ = C_im[t];
    lamr[t] = lr; lami[t] = li; dtr[t] = dr; dti[t] = di;
    c2r[t] = 2.0f * (crv * qr - civ * qi);
    c2i[t] = 2.0f * (crv * qi + civ * qr);
}

// ---------------------------------------------------------------------------
// Build KA[i][h][t] (bf16): reversed, zero-padded conv kernel.
// 4-way n-chain interleave for ILP (bit-exact: each acc[k] still sums its
// terms in ascending-n order; only the 4 independent rotation chains run
// in parallel, hiding the 2-fma/step dependency latency).
// ---------------------------------------------------------------------------
__global__ void kq_k(const float* __restrict__ lamr, const float* __restrict__ lami,
                     const float* __restrict__ dtr,  const float* __restrict__ dti,
                     const float* __restrict__ c2r,  const float* __restrict__ c2i,
                     u16* __restrict__ KA)
{
    int t = blockIdx.x * 256 + threadIdx.x;   // < 6*512*49
    int dc = t % 49;
    int ih = t / 49;                          // i*HD + h
    int d0 = dc * 16;
    float acc[16];
#pragma unroll
    for (int k = 0; k < 16; k++) acc[k] = 0.f;
    int base = ih * 64;
    for (int n = 0; n < 64; n += 4) {
        float lr[4], li[4], cr[4], ci[4], pr[4], pi[4];
#pragma unroll
        for (int j = 0; j < 4; j++) {
            int q = base + n + j;
            lr[j] = lamr[q]; li[j] = lami[q];
            float dr = dtr[q], di = dti[q];
            cr[j] = c2r[q]; ci[j] = c2i[q];
            float e = __expf(dr * (float)d0);
            float sn, cs; __sincosf(di * (float)d0, &sn, &cs);
            pr[j] = e * cs; pi[j] = e * sn;   // lam^d0
        }
#pragma unroll
        for (int k = 0; k < 16; k++) {
#pragma unroll
            for (int j = 0; j < 4; j++) {
                acc[k] = fmaf(cr[j], pr[j], fmaf(-ci[j], pi[j], acc[k]));
                float nr = pr[j] * lr[j] - pi[j] * li[j];
                pi[j] = fmaf(pr[j], li[j], pi[j] * lr[j]);
                pr[j] = nr;
            }
        }
    }
    u16* kap = KA + (size_t)ih * NKA;
#pragma unroll
    for (int k = 0; k < 16; k++)
        kap[TOFF - (d0 + k)] = (u16)f2b(acc[k]);
    if (dc == 0)  for (int z = TOFF + 1; z < NKA; z++) kap[z] = 0;
    if (dc == 48) for (int z = 0; z < TOFF - 783; z++) kap[z] = 0;
}

// ---------------------------------------------------------------------------
// Transpose x[b][l] -> xT[l][b] (200 KB, L2-resident; cost ~2 us)
// ---------------------------------------------------------------------------
__global__ void xt_k(const float* __restrict__ x, float* __restrict__ xT)
{
    int t = blockIdx.x * 256 + threadIdx.x;   // < 784*64
    int l = t >> 6, b = t & 63;
    xT[t] = x[b * LSEQ + l];
}

// ---------------------------------------------------------------------------
// Encoder: thread = (l, h, b-oct).  Extended to LPADROWS: pad rows get ZEROS
// (lnT never writes them, so they stay 0 across all layers; conv staging
// reads them as deterministic zeros).
// ---------------------------------------------------------------------------
__global__ void encoder_k(const float* __restrict__ xT, const float* __restrict__ ew,
                          const float* __restrict__ eb, u16* __restrict__ Vb)
{
    int g = blockIdx.x * 256 + threadIdx.x;   // < 800*512*8
    int bo = g & 7;
    int h  = (g >> 3) & 511;
    int l  = g >> 12;
    uint4* dst = (uint4*)&Vb[((size_t)l * HD + h) * BB + 8 * bo];
    if (l >= LSEQ) { *dst = (uint4){0, 0, 0, 0}; return; }
    const float4* xp = (const float4*)&xT[l * BB + 8 * bo];
    float4 a0 = xp[0], a1 = xp[1];
    float w = ew[h], bb = eb[h];
    unsigned p0 = f2b(fmaf(a0.x, w, bb)) | (f2b(fmaf(a0.y, w, bb)) << 16);
    unsigned p1 = f2b(fmaf(a0.z, w, bb)) | (f2b(fmaf(a0.w, w, bb)) << 16);
    unsigned p2 = f2b(fmaf(a1.x, w, bb)) | (f2b(fmaf(a1.y, w, bb)) << 16);
    unsigned p3 = f2b(fmaf(a1.z, w, bb)) | (f2b(fmaf(a1.w, w, bb)) << 16);
    *dst = (uint4){p0, p1, p2, p3};
}

// ---------------------------------------------------------------------------
// MFMA causal-Toeplitz conv + residual via 32x32x16 bf16 MFMA.
// ROUND-0 STRUCTURE VERBATIM (measured 56.5 us/layer): c-major ascending
// (h fastest), no fused LN, loads issued and consumed in-iteration.
// ---------------------------------------------------------------------------
__global__ __launch_bounds__(128, 4)
void conv_k(const u16* __restrict__ Vb, u16* __restrict__ V2,
            const u16* __restrict__ KA, const float* __restrict__ Dvec)
{
    __shared__ __align__(16) u16 KR[6816];           // 8 shifted copies
    __shared__ __align__(16) unsigned UT[2][64 * UTS2];

    const int thr = threadIdx.x;
    const int h   = blockIdx.x & 511;
    const int c   = blockIdx.x >> 9;         // 0..4
    const int w   = thr >> 6;                // b-half (n-tile)
    const int lane = thr & 63;
    const int n2 = lane & 31;
    const int qp = lane >> 5;
    const int JTN = 10 * c + 10;

    const u16* kap = KA + (size_t)h * NKA;
    {
        int s = thr & 7, ch = thr >> 3;      // 16 chunks x 53 (covers 848)
        int i0 = ch * 53;
        int i1 = (i0 + 53 < NKA) ? (i0 + 53) : NKA;
        u16* kr = KR + KSTR * s + ((8 - s) & 7);
        for (int i = i0; i < i1; i++) kr[i] = kap[i];
    }

    const int jj = thr >> 4;
    const int bq = thr & 15;
    {   // stage tile jt=0 (j rows 0..15)
        const u16* p = &Vb[((size_t)(2 * jj) * HD + h) * BB + 4 * bq];
        u4h r0 = *(const u4h*)p;
        u4h r1 = *(const u4h*)(p + (size_t)HD * BB);
        unsigned* up = &UT[0][0];
#pragma unroll
        for (int i = 0; i < 4; i++)
            up[(4 * bq + i) * UTS2 + jj] = (unsigned)r0[i] | ((unsigned)r1[i] << 16);
    }
    __syncthreads();

    f16v acc[CHK2];
#pragma unroll
    for (int i = 0; i < CHK2; i++)
#pragma unroll
        for (int r = 0; r < 16; r++) acc[i][r] = 0.f;

    const float dcoef = 1.0f + Dvec[h];

    const int s = lane & 7;
    const u16* krb = KR + KSTR * s + ((8 - s) & 7)
                     + (TOFF - 160 * c) + 8 * qp - n2;
    const unsigned* bb0 = &UT[0][(32 * w + n2) * UTS2 + 4 * qp];
    const unsigned* bb1 = &UT[1][(32 * w + n2) * UTS2 + 4 * qp];

    for (int jt = 0; jt < JTN; ++jt) {
        u4h r0, r1;
        const bool more = (jt + 1) < JTN;
        if (more) {
            int j = 16 * (jt + 1) + 2 * jj;
            const u16* p = &Vb[((size_t)j * HD + h) * BB + 4 * bq];
            r0 = *(const u4h*)p;
            r1 = *(const u4h*)(p + (size_t)HD * BB);
        }
        const unsigned* bb = (jt & 1) ? bb1 : bb0;
        union { unsigned u[4]; s8v v; } bu;
        bu.u[0] = bb[0]; bu.u[1] = bb[1]; bu.u[2] = bb[2]; bu.u[3] = bb[3];

        const u16* ap0 = krb + 16 * jt;
#pragma unroll
        for (int lt = 0; lt < CHK2; ++lt) {
            if (jt > 10 * c + 2 * lt + 1) continue;   // tile done (uniform)
            s8v av = *(const s8v*)__builtin_assume_aligned(ap0 - 32 * lt, 16);
            acc[lt] = __builtin_amdgcn_mfma_f32_32x32x16_bf16(av, bu.v, acc[lt], 0, 0, 0);
        }
        if (more) {
            unsigned* up = &UT[(jt & 1) ^ 1][0];
#pragma unroll
            for (int i = 0; i < 4; i++)
                up[(4 * bq + i) * UTS2 + jj] = (unsigned)r0[i] | ((unsigned)r1[i] << 16);
        }
        __syncthreads();
    }

    // epilogue: V2 = bf16(y + (1+D)*u)
#pragma unroll
    for (int lt = 0; lt < CHK2; ++lt) {
        const int l0 = 32 * (5 * c + lt) + 4 * qp;
#pragma unroll
        for (int r = 0; r < 16; ++r) {
            int l = l0 + (r & 3) + 8 * (r >> 2);
            size_t a = ((size_t)l * HD + h) * BB + 32 * w + n2;
            V2[a] = (u16)f2b(fmaf(dcoef, b2f16(Vb[a]), acc[lt][r]));
        }
    }
}

// ---------------------------------------------------------------------------
// LayerNorm over h in [l][h][b]; bf16 in/out, fp32 math, u8h (16B) I/O.
// Block = one l, 512 thr: thread (bo = b-oct 0..7, hg = h-group-of-8 0..63).
// ---------------------------------------------------------------------------
__global__ __launch_bounds__(512)
void lnT_k(const u16* __restrict__ src, u16* __restrict__ dst,
           const float* __restrict__ gp, const float* __restrict__ bp)
{
    __shared__ float redS[64][65], redQ[64][65];
    __shared__ float mus[64], rss[64];
    __shared__ float gs[512], bs[512];
    const int thr = threadIdx.x;
    const int bo = thr & 7;           // b = 8*bo + i
    const int hg = thr >> 3;          // h = 8*hg + k
    const size_t l = blockIdx.x;
    gs[thr] = gp[thr]; bs[thr] = bp[thr];

    const u16* sp = &src[(l * HD + hg * 8) * BB + 8 * bo];
    float v[64];                       // v[k*8+i]
    float s[8] = {0, 0, 0, 0, 0, 0, 0, 0};
    float q[8] = {0, 0, 0, 0, 0, 0, 0, 0};
#pragma unroll
    for (int k = 0; k < 8; k++) {
        u8h r = *(const u8h*)(sp + (size_t)k * BB);
#pragma unroll
        for (int i = 0; i < 8; i++) {
            float x = b2f16(r[i]);
            v[k * 8 + i] = x;
            s[i] += x;
            q[i] = fmaf(x, x, q[i]);
        }
    }
#pragma unroll
    for (int i = 0; i < 8; i++) { redS[hg][8 * bo + i] = s[i]; redQ[hg][8 * bo + i] = q[i]; }
    __syncthreads();
    if (thr < 64) {
        float ts = 0.f, tq = 0.f;
#pragma unroll
        for (int g = 0; g < 64; g++) { ts += redS[g][thr]; tq += redQ[g][thr]; }
        float mu = ts * (1.0f / HD);
        mus[thr] = mu;
        rss[thr] = rsqrtf(tq * (1.0f / HD) - mu * mu + 1e-5f);
    }
    __syncthreads();
    float mu[8], rs[8];
#pragma unroll
    for (int i = 0; i < 8; i++) { mu[i] = mus[8 * bo + i]; rs[i] = rss[8 * bo + i]; }
    u16* dp = &dst[(l * HD + hg * 8) * BB + 8 * bo];
#pragma unroll
    for (int k = 0; k < 8; k++) {
        float g = gs[hg * 8 + k], bb = bs[hg * 8 + k];
        u8h w;
#pragma unroll
        for (int i = 0; i < 8; i++)
            w[i] = (u16)f2b(fmaf((v[k * 8 + i] - mu[i]) * rs[i], g, bb));
        *(u8h*)(dp + (size_t)k * BB) = w;
    }
}

// ---------------------------------------------------------------------------
// Self-contained DOUBLE LayerNorm (layer-5 LN + final LN in one pass):
// block = one l holds the full h-row, so it computes both stats itself.
// u6 = LN(P5; g5,b5) kept in f32 registers (no intermediate bf16 round),
// out = LN(u6; g,b) -> bf16.  Saves one full 103 MB stream pass.
// ---------------------------------------------------------------------------
__global__ __launch_bounds__(512)
void lnT2s_k(const u16* __restrict__ src, u16* __restrict__ dst,
             const float* __restrict__ g5p, const float* __restrict__ b5p,
             const float* __restrict__ gp, const float* __restrict__ bp)
{
    __shared__ float redS[64][65], redQ[64][65];
    __shared__ float mu1s[64], rs1s[64], mu2s[64], rs2s[64];
    __shared__ float gs[512], bs[512];
    const int thr = threadIdx.x;
    const int bo = thr & 7;           // b = 8*bo + i
    const int hg = thr >> 3;          // h = 8*hg + k
    const size_t l = blockIdx.x;
    gs[thr] = gp[thr]; bs[thr] = bp[thr];

    const u16* sp = &src[(l * HD + (size_t)hg * 8) * BB + 8 * bo];
    float v[64];                       // v[k*8+i]
    float s[8] = {0, 0, 0, 0, 0, 0, 0, 0};
    float q[8] = {0, 0, 0, 0, 0, 0, 0, 0};
#pragma unroll
    for (int k = 0; k < 8; k++) {
        u8h r = *(const u8h*)(sp + (size_t)k * BB);
#pragma unroll
        for (int i = 0; i < 8; i++) {
            float x = b2f16(r[i]);
            v[k * 8 + i] = x;
            s[i] += x;
            q[i] = fmaf(x, x, q[i]);
        }
    }
#pragma unroll
    for (int i = 0; i < 8; i++) { redS[hg][8 * bo + i] = s[i]; redQ[hg][8 * bo + i] = q[i]; }
    __syncthreads();
    if (thr < 64) {
        float ts = 0.f, tq = 0.f;
#pragma unroll
        for (int g = 0; g < 64; g++) { ts += redS[g][thr]; tq += redQ[g][thr]; }
        float mu = ts * (1.0f / HD);
        mu1s[thr] = mu;
        rs1s[thr] = rsqrtf(tq * (1.0f / HD) - mu * mu + 1e-5f);
    }
    __syncthreads();
    float mu1[8], rs1[8];
#pragma unroll
    for (int i = 0; i < 8; i++) { mu1[i] = mu1s[8 * bo + i]; rs1[i] = rs1s[8 * bo + i]; }

    // second LN pass in registers: u6 = (v - mu1)*rs1*g5 + b5
    float s2[8] = {0, 0, 0, 0, 0, 0, 0, 0};
    float q2[8] = {0, 0, 0, 0, 0, 0, 0, 0};
#pragma unroll
    for (int k = 0; k < 8; k++) {
        float g5 = g5p[hg * 8 + k], b5 = b5p[hg * 8 + k];
#pragma unroll
        for (int i = 0; i < 8; i++) {
            float x = fmaf((v[k * 8 + i] - mu1[i]) * rs1[i], g5, b5);
            v[k * 8 + i] = x;
            s2[i] += x;
            q2[i] = fmaf(x, x, q2[i]);
        }
    }
#pragma unroll
    for (int i = 0; i < 8; i++) { redS[hg][8 * bo + i] = s2[i]; redQ[hg][8 * bo + i] = q2[i]; }
    __syncthreads();
    if (thr < 64) {
        float ts = 0.f, tq = 0.f;
#pragma unroll
        for (int g = 0; g < 64; g++) { ts += redS[g][thr]; tq += redQ[g][thr]; }
        float mu = ts * (1.0f / HD);
        mu2s[thr] = mu;
        rs2s[thr] = rsqrtf(tq * (1.0f / HD) - mu * mu + 1e-5f);
    }
    __syncthreads();
    float mu2[8], rs2[8];
#pragma unroll
    for (int i = 0; i < 8; i++) { mu2[i] = mu2s[8 * bo + i]; rs2[i] = rs2s[8 * bo + i]; }
    u16* dp = &dst[(l * HD + (size_t)hg * 8) * BB + 8 * bo];
#pragma unroll
    for (int k = 0; k < 8; k++) {
        float g = gs[hg * 8 + k], bb = bs[hg * 8 + k];
        u8h wv;
#pragma unroll
        for (int i = 0; i < 8; i++)
            wv[i] = (u16)f2b(fmaf((v[k * 8 + i] - mu2[i]) * rs2[i], g, bb));
        *(u8h*)(dp + (size_t)k * BB) = wv;
    }
}

// ---------------------------------------------------------------------------
// Mean-pool over l from bf16 Vb: PO[h*64+b] = mean_l Vb[l][h][b].
// ---------------------------------------------------------------------------
__global__ void pool_k(const u16* __restrict__ Vb, float* __restrict__ PO)
{
    __shared__ float red[4][64];
    int h = blockIdx.x;
    int b = threadIdx.x & 63;
    int lg = threadIdx.x >> 6;               // 0..3
    const u16* p = &Vb[(size_t)h * BB + b];
    float s = 0.f;
    for (int l = lg; l < LSEQ; l += 4) s += b2f16(p[(size_t)l * HD * BB]);
    red[lg][b] = s;
    __syncthreads();
    if (threadIdx.x < 64) {
        float t = red[0][b] + red[1][b] + red[2][b] + red[3][b];
        PO[h * BB + b] = t * (1.0f / LSEQ);
    }
}

// ---------------------------------------------------------------------------
// Decoder: out[b,c] = PO[:,b] . dec_w[:,c] + dec_b[c]
// ---------------------------------------------------------------------------
__global__ void dec_k(const float* __restrict__ PO, const float* __restrict__ w,
                      const float* __restrict__ bias, float* __restrict__ out)
{
    int t = blockIdx.x * 256 + threadIdx.x;
    if (t >= BB * 10) return;
    int cc = t % 10, b = t / 10;
    float acc = bias[cc];
    for (int hh = 0; hh < HD; hh++)
        acc = fmaf(PO[hh * BB + b], w[hh * 10 + cc], acc);
    out[t] = acc;
}

// ---------------------------------------------------------------------------
extern "C" void kernel_launch(void* const* d_in, const int* in_sizes, int n_in,
                              void* d_out, int out_size, void* d_ws, size_t ws_size,
                              hipStream_t stream)
{
    const float* x   = (const float*)d_in[0];
    const float* ew  = (const float*)d_in[1];
    const float* eb  = (const float*)d_in[2];
    const float* ldt = (const float*)d_in[3];
    const float* lar = (const float*)d_in[4];
    const float* aim = (const float*)d_in[5];
    const float* cre = (const float*)d_in[6];
    const float* cim = (const float*)d_in[7];
    const float* Dp  = (const float*)d_in[8];
    const float* lng = (const float*)d_in[9];
    const float* lnb = (const float*)d_in[10];
    const float* fng = (const float*)d_in[11];
    const float* fnb = (const float*)d_in[12];
    const float* dw  = (const float*)d_in[13];
    const float* db  = (const float*)d_in[14];
    float* out = (float*)d_out;

    const size_t SZB = (size_t)BB * LPADROWS * HD;   // 26,214,400 u16 slots
    const size_t PP  = (size_t)NLAY * HD * NST;      // 196,608
    u16*   Vb  = (u16*)d_ws;                // bf16 residual stream [l][h][b]
    u16*   V2  = Vb + SZB;                  // bf16 pre-LN buffer
    float* PAR = (float*)(V2 + SZB);
    float* lamr = PAR,        * lami = PAR + PP;
    float* dtr  = PAR + 2*PP, * dti  = PAR + 3*PP;
    float* c2r  = PAR + 4*PP, * c2i  = PAR + 5*PP;
    u16* KA = (u16*)(PAR + 6 * PP);                  // 6*512*848 u16
    float* PO = PAR + 6 * PP + (NLAY * HD * NKA) / 2;
    float* xT = PO + BB * HD;                        // 784*64 fp32

    precompute_k<<<(NLAY * HD * NST + 255) / 256, 256, 0, stream>>>(
        ldt, lar, aim, cre, cim, lamr, lami, dtr, dti, c2r, c2i);
    kq_k<<<(NLAY * HD * 49) / 256, 256, 0, stream>>>(
        lamr, lami, dtr, dti, c2r, c2i, KA);
    xt_k<<<(LSEQ * BB) / 256, 256, 0, stream>>>(x, xT);
    encoder_k<<<(LPADROWS * HD * 8) / 256, 256, 0, stream>>>(xT, ew, eb, Vb);

    // layers 0..4: conv (Vb -> V2), LN (V2 -> Vb)
    for (int i = 0; i < NLAY - 1; i++) {
        conv_k<<<512 * NCH, 128, 0, stream>>>(
            Vb, V2, KA + (size_t)i * HD * NKA, Dp + i * HD);
        lnT_k<<<LSEQ, 512, 0, stream>>>(V2, Vb, lng + i * HD, lnb + i * HD);
    }
    // layer 5: conv, then fused LN5 + final LN in one pass
    conv_k<<<512 * NCH, 128, 0, stream>>>(
        Vb, V2, KA + (size_t)5 * HD * NKA, Dp + 5 * HD);
    lnT2s_k<<<LSEQ, 512, 0, stream>>>(V2, Vb, lng + 5 * HD, lnb + 5 * HD, fng, fnb);

    pool_k<<<HD, 256, 0, stream>>>(Vb, PO);
    dec_k<<<(BB * 10 + 255) / 256, 256, 0, stream>>>(PO, dw, db, out);
}

// Round 9
// 554.030 us; speedup vs baseline: 3.6093x; 1.1227x over previous
//
#include <hip/hip_runtime.h>
#include <hip/hip_bf16.h>

#define HD 512      // d_model
#define NST 64      // d_state
#define NLAY 6
#define LSEQ 784
#define BB 64       // batch
#define NKA 848     // reversed+padded kernel array length (u16)
#define TOFF 800    // KA[t] = K[TOFF - t]; t in [17,800] real, else 0
#define LPADROWS 800  // padded L (25 tiles of 32); pad rows killed by zero-K
#define KSTR 850    // u16 stride between shifted K copies
#define CHK2 5      // 32-row l-tiles per conv block; 25 = 5*5
#define NCH 5       // chunks
#define UTS2 9      // UT row stride in dwords (8 j-pairs + 1 pad)

typedef unsigned short u16;
typedef short s8v __attribute__((ext_vector_type(8)));   // 8 bf16 (4 VGPR)
typedef float f16v __attribute__((ext_vector_type(16))); // 32x32 MFMA acc
typedef u16  u4h __attribute__((ext_vector_type(4)));    // ushort4 (8B)
typedef u16  u8h __attribute__((ext_vector_type(8)));    // ushort8 (16B)

// fp32 -> bf16 bits, round-to-nearest-even
__device__ __forceinline__ unsigned f2b(float f)
{
    unsigned u = __builtin_bit_cast(unsigned, f);
    return (u + 0x7FFFu + ((u >> 16) & 1u)) >> 16;
}
__device__ __forceinline__ float b2f16(u16 v)
{
    unsigned u = ((unsigned)v) << 16;
    return __builtin_bit_cast(float, u);
}

// ---------------------------------------------------------------------------
// Per (layer,h,n): lambda = exp(dt*A), dtA, 2*Cd. Layout [i][h][n].
// ---------------------------------------------------------------------------
__global__ void precompute_k(const float* __restrict__ log_dt,
                             const float* __restrict__ log_A_real,
                             const float* __restrict__ A_imag,
                             const float* __restrict__ C_re,
                             const float* __restrict__ C_im,
                             float* __restrict__ lamr, float* __restrict__ lami,
                             float* __restrict__ dtr,  float* __restrict__ dti,
                             float* __restrict__ c2r,  float* __restrict__ c2i)
{
    int t = blockIdx.x * 256 + threadIdx.x;
    if (t >= NLAY * HD * NST) return;
    int ih = t >> 6;                       // i*HD + h
    float dt  = expf(log_dt[ih]);
    float are = -expf(log_A_real[t]);
    float aim = A_imag[t];
    float dr = are * dt, di = aim * dt;
    float er = expf(dr);
    float sn, cs; __sincosf(di, &sn, &cs);
    float lr = er * cs, li = er * sn;      // lambda
    float e1r = lr - 1.0f, e1i = li;
    float den = are * are + aim * aim;
    float qr = (e1r * are + e1i * aim) / den;
    float qi = (e1i * are - e1r * aim) / den;
    float crv = C_re[t], civ = C_im[t];
    lamr[t] = lr; lami[t] = li; dtr[t] = dr; dti[t] = di;
    c2r[t] = 2.0f * (crv * qr - civ * qi);
    c2i[t] = 2.0f * (crv * qi + civ * qr);
}

// ---------------------------------------------------------------------------
// Build KA[i][h][t] (bf16): reversed, zero-padded conv kernel.
// 4-way n-chain interleave for ILP (bit-exact: each acc[k] still sums its
// terms in ascending-n order; only the 4 independent rotation chains run
// in parallel, hiding the 2-fma/step dependency latency).
// ---------------------------------------------------------------------------
__global__ void kq_k(const float* __restrict__ lamr, const float* __restrict__ lami,
                     const float* __restrict__ dtr,  const float* __restrict__ dti,
                     const float* __restrict__ c2r,  const float* __restrict__ c2i,
                     u16* __restrict__ KA)
{
    int t = blockIdx.x * 256 + threadIdx.x;   // < 6*512*49
    int dc = t % 49;
    int ih = t / 49;                          // i*HD + h
    int d0 = dc * 16;
    float acc[16];
#pragma unroll
    for (int k = 0; k < 16; k++) acc[k] = 0.f;
    int base = ih * 64;
    for (int n = 0; n < 64; n += 4) {
        float lr[4], li[4], cr[4], ci[4], pr[4], pi[4];
#pragma unroll
        for (int j = 0; j < 4; j++) {
            int q = base + n + j;
            lr[j] = lamr[q]; li[j] = lami[q];
            float dr = dtr[q], di = dti[q];
            cr[j] = c2r[q]; ci[j] = c2i[q];
            float e = __expf(dr * (float)d0);
            float sn, cs; __sincosf(di * (float)d0, &sn, &cs);
            pr[j] = e * cs; pi[j] = e * sn;   // lam^d0
        }
#pragma unroll
        for (int k = 0; k < 16; k++) {
#pragma unroll
            for (int j = 0; j < 4; j++) {
                acc[k] = fmaf(cr[j], pr[j], fmaf(-ci[j], pi[j], acc[k]));
                float nr = pr[j] * lr[j] - pi[j] * li[j];
                pi[j] = fmaf(pr[j], li[j], pi[j] * lr[j]);
                pr[j] = nr;
            }
        }
    }
    u16* kap = KA + (size_t)ih * NKA;
#pragma unroll
    for (int k = 0; k < 16; k++)
        kap[TOFF - (d0 + k)] = (u16)f2b(acc[k]);
    if (dc == 0)  for (int z = TOFF + 1; z < NKA; z++) kap[z] = 0;
    if (dc == 48) for (int z = 0; z < TOFF - 783; z++) kap[z] = 0;
}

// ---------------------------------------------------------------------------
// Transpose x[b][l] -> xT[l][b] (200 KB, L2-resident; cost ~2 us)
// ---------------------------------------------------------------------------
__global__ void xt_k(const float* __restrict__ x, float* __restrict__ xT)
{
    int t = blockIdx.x * 256 + threadIdx.x;   // < 784*64
    int l = t >> 6, b = t & 63;
    xT[t] = x[b * LSEQ + l];
}

// ---------------------------------------------------------------------------
// Encoder: thread = (l, h, b-oct).  Extended to LPADROWS: pad rows get ZEROS
// (lnT never writes them, so they stay 0 across all layers; conv staging
// reads them as deterministic zeros).
// ---------------------------------------------------------------------------
__global__ void encoder_k(const float* __restrict__ xT, const float* __restrict__ ew,
                          const float* __restrict__ eb, u16* __restrict__ Vb)
{
    int g = blockIdx.x * 256 + threadIdx.x;   // < 800*512*8
    int bo = g & 7;
    int h  = (g >> 3) & 511;
    int l  = g >> 12;
    uint4* dst = (uint4*)&Vb[((size_t)l * HD + h) * BB + 8 * bo];
    if (l >= LSEQ) { *dst = (uint4){0, 0, 0, 0}; return; }
    const float4* xp = (const float4*)&xT[l * BB + 8 * bo];
    float4 a0 = xp[0], a1 = xp[1];
    float w = ew[h], bb = eb[h];
    unsigned p0 = f2b(fmaf(a0.x, w, bb)) | (f2b(fmaf(a0.y, w, bb)) << 16);
    unsigned p1 = f2b(fmaf(a0.z, w, bb)) | (f2b(fmaf(a0.w, w, bb)) << 16);
    unsigned p2 = f2b(fmaf(a1.x, w, bb)) | (f2b(fmaf(a1.y, w, bb)) << 16);
    unsigned p3 = f2b(fmaf(a1.z, w, bb)) | (f2b(fmaf(a1.w, w, bb)) << 16);
    *dst = (uint4){p0, p1, p2, p3};
}

// ---------------------------------------------------------------------------
// MFMA causal-Toeplitz conv + residual via 32x32x16 bf16 MFMA.
// Round-8 structure; ONE change: LPT dispatch (c = 4 - bid>>9) so the 512
// longest blocks (c=4, 50 iters) launch first and short c=0 blocks backfill
// the tail.  h-fastest within each c-group preserved (L2 reuse intact, r2).
// ---------------------------------------------------------------------------
__global__ __launch_bounds__(128, 4)
void conv_k(const u16* __restrict__ Vb, u16* __restrict__ V2,
            const u16* __restrict__ KA, const float* __restrict__ Dvec)
{
    __shared__ __align__(16) u16 KR[6816];           // 8 shifted copies
    __shared__ __align__(16) unsigned UT[2][64 * UTS2];

    const int thr = threadIdx.x;
    const int h   = blockIdx.x & 511;
    const int c   = NCH - 1 - (blockIdx.x >> 9);     // 4,...,0 (LPT order)
    const int w   = thr >> 6;                // b-half (n-tile)
    const int lane = thr & 63;
    const int n2 = lane & 31;
    const int qp = lane >> 5;
    const int JTN = 10 * c + 10;

    const u16* kap = KA + (size_t)h * NKA;
    {
        int s = thr & 7, ch = thr >> 3;      // 16 chunks x 53 (covers 848)
        int i0 = ch * 53;
        int i1 = (i0 + 53 < NKA) ? (i0 + 53) : NKA;
        u16* kr = KR + KSTR * s + ((8 - s) & 7);
        for (int i = i0; i < i1; i++) kr[i] = kap[i];
    }

    const int jj = thr >> 4;
    const int bq = thr & 15;
    {   // stage tile jt=0 (j rows 0..15)
        const u16* p = &Vb[((size_t)(2 * jj) * HD + h) * BB + 4 * bq];
        u4h r0 = *(const u4h*)p;
        u4h r1 = *(const u4h*)(p + (size_t)HD * BB);
        unsigned* up = &UT[0][0];
#pragma unroll
        for (int i = 0; i < 4; i++)
            up[(4 * bq + i) * UTS2 + jj] = (unsigned)r0[i] | ((unsigned)r1[i] << 16);
    }
    __syncthreads();

    f16v acc[CHK2];
#pragma unroll
    for (int i = 0; i < CHK2; i++)
#pragma unroll
        for (int r = 0; r < 16; r++) acc[i][r] = 0.f;

    const float dcoef = 1.0f + Dvec[h];

    const int s = lane & 7;
    const u16* krb = KR + KSTR * s + ((8 - s) & 7)
                     + (TOFF - 160 * c) + 8 * qp - n2;
    const unsigned* bb0 = &UT[0][(32 * w + n2) * UTS2 + 4 * qp];
    const unsigned* bb1 = &UT[1][(32 * w + n2) * UTS2 + 4 * qp];

    for (int jt = 0; jt < JTN; ++jt) {
        u4h r0, r1;
        const bool more = (jt + 1) < JTN;
        if (more) {
            int j = 16 * (jt + 1) + 2 * jj;
            const u16* p = &Vb[((size_t)j * HD + h) * BB + 4 * bq];
            r0 = *(const u4h*)p;
            r1 = *(const u4h*)(p + (size_t)HD * BB);
        }
        const unsigned* bb = (jt & 1) ? bb1 : bb0;
        union { unsigned u[4]; s8v v; } bu;
        bu.u[0] = bb[0]; bu.u[1] = bb[1]; bu.u[2] = bb[2]; bu.u[3] = bb[3];

        const u16* ap0 = krb + 16 * jt;
#pragma unroll
        for (int lt = 0; lt < CHK2; ++lt) {
            if (jt > 10 * c + 2 * lt + 1) continue;   // tile done (uniform)
            s8v av = *(const s8v*)__builtin_assume_aligned(ap0 - 32 * lt, 16);
            acc[lt] = __builtin_amdgcn_mfma_f32_32x32x16_bf16(av, bu.v, acc[lt], 0, 0, 0);
        }
        if (more) {
            unsigned* up = &UT[(jt & 1) ^ 1][0];
#pragma unroll
            for (int i = 0; i < 4; i++)
                up[(4 * bq + i) * UTS2 + jj] = (unsigned)r0[i] | ((unsigned)r1[i] << 16);
        }
        __syncthreads();
    }

    // epilogue: V2 = bf16(y + (1+D)*u)
#pragma unroll
    for (int lt = 0; lt < CHK2; ++lt) {
        const int l0 = 32 * (5 * c + lt) + 4 * qp;
#pragma unroll
        for (int r = 0; r < 16; ++r) {
            int l = l0 + (r & 3) + 8 * (r >> 2);
            size_t a = ((size_t)l * HD + h) * BB + 32 * w + n2;
            V2[a] = (u16)f2b(fmaf(dcoef, b2f16(Vb[a]), acc[lt][r]));
        }
    }
}

// ---------------------------------------------------------------------------
// LayerNorm over h in [l][h][b]; bf16 in/out, fp32 math, u8h (16B) I/O.
// Block = one l, 512 thr: thread (bo = b-oct 0..7, hg = h-group-of-8 0..63).
// ---------------------------------------------------------------------------
__global__ __launch_bounds__(512)
void lnT_k(const u16* __restrict__ src, u16* __restrict__ dst,
           const float* __restrict__ gp, const float* __restrict__ bp)
{
    __shared__ float redS[64][65], redQ[64][65];
    __shared__ float mus[64], rss[64];
    __shared__ float gs[512], bs[512];
    const int thr = threadIdx.x;
    const int bo = thr & 7;           // b = 8*bo + i
    const int hg = thr >> 3;          // h = 8*hg + k
    const size_t l = blockIdx.x;
    gs[thr] = gp[thr]; bs[thr] = bp[thr];

    const u16* sp = &src[(l * HD + hg * 8) * BB + 8 * bo];
    float v[64];                       // v[k*8+i]
    float s[8] = {0, 0, 0, 0, 0, 0, 0, 0};
    float q[8] = {0, 0, 0, 0, 0, 0, 0, 0};
#pragma unroll
    for (int k = 0; k < 8; k++) {
        u8h r = *(const u8h*)(sp + (size_t)k * BB);
#pragma unroll
        for (int i = 0; i < 8; i++) {
            float x = b2f16(r[i]);
            v[k * 8 + i] = x;
            s[i] += x;
            q[i] = fmaf(x, x, q[i]);
        }
    }
#pragma unroll
    for (int i = 0; i < 8; i++) { redS[hg][8 * bo + i] = s[i]; redQ[hg][8 * bo + i] = q[i]; }
    __syncthreads();
    if (thr < 64) {
        float ts = 0.f, tq = 0.f;
#pragma unroll
        for (int g = 0; g < 64; g++) { ts += redS[g][thr]; tq += redQ[g][thr]; }
        float mu = ts * (1.0f / HD);
        mus[thr] = mu;
        rss[thr] = rsqrtf(tq * (1.0f / HD) - mu * mu + 1e-5f);
    }
    __syncthreads();
    float mu[8], rs[8];
#pragma unroll
    for (int i = 0; i < 8; i++) { mu[i] = mus[8 * bo + i]; rs[i] = rss[8 * bo + i]; }
    u16* dp = &dst[(l * HD + hg * 8) * BB + 8 * bo];
#pragma unroll
    for (int k = 0; k < 8; k++) {
        float g = gs[hg * 8 + k], bb = bs[hg * 8 + k];
        u8h w;
#pragma unroll
        for (int i = 0; i < 8; i++)
            w[i] = (u16)f2b(fmaf((v[k * 8 + i] - mu[i]) * rs[i], g, bb));
        *(u8h*)(dp + (size_t)k * BB) = w;
    }
}

// ---------------------------------------------------------------------------
// Self-contained DOUBLE LayerNorm (layer-5 LN + final LN in one pass):
// block = one l holds the full h-row, so it computes both stats itself.
// u6 = LN(P5; g5,b5) kept in f32 registers (no intermediate bf16 round),
// out = LN(u6; g,b) -> bf16.  Saves one full 103 MB stream pass.
// ---------------------------------------------------------------------------
__global__ __launch_bounds__(512)
void lnT2s_k(const u16* __restrict__ src, u16* __restrict__ dst,
             const float* __restrict__ g5p, const float* __restrict__ b5p,
             const float* __restrict__ gp, const float* __restrict__ bp)
{
    __shared__ float redS[64][65], redQ[64][65];
    __shared__ float mu1s[64], rs1s[64], mu2s[64], rs2s[64];
    __shared__ float gs[512], bs[512];
    const int thr = threadIdx.x;
    const int bo = thr & 7;           // b = 8*bo + i
    const int hg = thr >> 3;          // h = 8*hg + k
    const size_t l = blockIdx.x;
    gs[thr] = gp[thr]; bs[thr] = bp[thr];

    const u16* sp = &src[(l * HD + (size_t)hg * 8) * BB + 8 * bo];
    float v[64];                       // v[k*8+i]
    float s[8] = {0, 0, 0, 0, 0, 0, 0, 0};
    float q[8] = {0, 0, 0, 0, 0, 0, 0, 0};
#pragma unroll
    for (int k = 0; k < 8; k++) {
        u8h r = *(const u8h*)(sp + (size_t)k * BB);
#pragma unroll
        for (int i = 0; i < 8; i++) {
            float x = b2f16(r[i]);
            v[k * 8 + i] = x;
            s[i] += x;
            q[i] = fmaf(x, x, q[i]);
        }
    }
#pragma unroll
    for (int i = 0; i < 8; i++) { redS[hg][8 * bo + i] = s[i]; redQ[hg][8 * bo + i] = q[i]; }
    __syncthreads();
    if (thr < 64) {
        float ts = 0.f, tq = 0.f;
#pragma unroll
        for (int g = 0; g < 64; g++) { ts += redS[g][thr]; tq += redQ[g][thr]; }
        float mu = ts * (1.0f / HD);
        mu1s[thr] = mu;
        rs1s[thr] = rsqrtf(tq * (1.0f / HD) - mu * mu + 1e-5f);
    }
    __syncthreads();
    float mu1[8], rs1[8];
#pragma unroll
    for (int i = 0; i < 8; i++) { mu1[i] = mu1s[8 * bo + i]; rs1[i] = rs1s[8 * bo + i]; }

    // second LN pass in registers: u6 = (v - mu1)*rs1*g5 + b5
    float s2[8] = {0, 0, 0, 0, 0, 0, 0, 0};
    float q2[8] = {0, 0, 0, 0, 0, 0, 0, 0};
#pragma unroll
    for (int k = 0; k < 8; k++) {
        float g5 = g5p[hg * 8 + k], b5 = b5p[hg * 8 + k];
#pragma unroll
        for (int i = 0; i < 8; i++) {
            float x = fmaf((v[k * 8 + i] - mu1[i]) * rs1[i], g5, b5);
            v[k * 8 + i] = x;
            s2[i] += x;
            q2[i] = fmaf(x, x, q2[i]);
        }
    }
#pragma unroll
    for (int i = 0; i < 8; i++) { redS[hg][8 * bo + i] = s2[i]; redQ[hg][8 * bo + i] = q2[i]; }
    __syncthreads();
    if (thr < 64) {
        float ts = 0.f, tq = 0.f;
#pragma unroll
        for (int g = 0; g < 64; g++) { ts += redS[g][thr]; tq += redQ[g][thr]; }
        float mu = ts * (1.0f / HD);
        mu2s[thr] = mu;
        rs2s[thr] = rsqrtf(tq * (1.0f / HD) - mu * mu + 1e-5f);
    }
    __syncthreads();
    float mu2[8], rs2[8];
#pragma unroll
    for (int i = 0; i < 8; i++) { mu2[i] = mu2s[8 * bo + i]; rs2[i] = rs2s[8 * bo + i]; }
    u16* dp = &dst[(l * HD + (size_t)hg * 8) * BB + 8 * bo];
#pragma unroll
    for (int k = 0; k < 8; k++) {
        float g = gs[hg * 8 + k], bb = bs[hg * 8 + k];
        u8h wv;
#pragma unroll
        for (int i = 0; i < 8; i++)
            wv[i] = (u16)f2b(fmaf((v[k * 8 + i] - mu2[i]) * rs2[i], g, bb));
        *(u8h*)(dp + (size_t)k * BB) = wv;
    }
}

// ---------------------------------------------------------------------------
// Coalesced two-stage mean-pool.
// pool2_k: 256 blocks = 16 column-chunks (cb) x 16 l-groups (lg).
// Each thread reads u8h (16B); a block reads 4KB CONTIGUOUS per l-row
// (vs 128B/wave in the old pool), 49 rows per block.  Partials -> PO2.
// ---------------------------------------------------------------------------
__global__ __launch_bounds__(256)
void pool2_k(const u16* __restrict__ Vb, float* __restrict__ PO2)
{
    const int cb = blockIdx.x & 15;
    const int lg = blockIdx.x >> 4;          // 0..15
    const int off = cb * 2048 + threadIdx.x * 8;
    const u16* p = Vb + (size_t)(lg * 49) * (HD * BB) + off;
    float s[8] = {0, 0, 0, 0, 0, 0, 0, 0};
    for (int l = 0; l < 49; l++) {
        u8h r = *(const u8h*)p;
        p += HD * BB;
#pragma unroll
        for (int i = 0; i < 8; i++) s[i] += b2f16(r[i]);
    }
    float* q = PO2 + (size_t)lg * (HD * BB) + off;
    *(float4*)q       = (float4){s[0], s[1], s[2], s[3]};
    *(float4*)(q + 4) = (float4){s[4], s[5], s[6], s[7]};
}

// poolr_k: PO[t] = (1/LSEQ) * sum_g PO2[g][t]   (t < HD*BB)
__global__ void poolr_k(const float* __restrict__ PO2, float* __restrict__ PO)
{
    int t = blockIdx.x * 256 + threadIdx.x;
    float s = 0.f;
#pragma unroll
    for (int g = 0; g < 16; g++) s += PO2[(size_t)g * (HD * BB) + t];
    PO[t] = s * (1.0f / LSEQ);
}

// ---------------------------------------------------------------------------
// Decoder: out[b,c] = PO[:,b] . dec_w[:,c] + dec_b[c]
// ---------------------------------------------------------------------------
__global__ void dec_k(const float* __restrict__ PO, const float* __restrict__ w,
                      const float* __restrict__ bias, float* __restrict__ out)
{
    int t = blockIdx.x * 256 + threadIdx.x;
    if (t >= BB * 10) return;
    int cc = t % 10, b = t / 10;
    float acc = bias[cc];
    for (int hh = 0; hh < HD; hh++)
        acc = fmaf(PO[hh * BB + b], w[hh * 10 + cc], acc);
    out[t] = acc;
}

// ---------------------------------------------------------------------------
extern "C" void kernel_launch(void* const* d_in, const int* in_sizes, int n_in,
                              void* d_out, int out_size, void* d_ws, size_t ws_size,
                              hipStream_t stream)
{
    const float* x   = (const float*)d_in[0];
    const float* ew  = (const float*)d_in[1];
    const float* eb  = (const float*)d_in[2];
    const float* ldt = (const float*)d_in[3];
    const float* lar = (const float*)d_in[4];
    const float* aim = (const float*)d_in[5];
    const float* cre = (const float*)d_in[6];
    const float* cim = (const float*)d_in[7];
    const float* Dp  = (const float*)d_in[8];
    const float* lng = (const float*)d_in[9];
    const float* lnb = (const float*)d_in[10];
    const float* fng = (const float*)d_in[11];
    const float* fnb = (const float*)d_in[12];
    const float* dw  = (const float*)d_in[13];
    const float* db  = (const float*)d_in[14];
    float* out = (float*)d_out;

    const size_t SZB = (size_t)BB * LPADROWS * HD;   // 26,214,400 u16 slots
    const size_t PP  = (size_t)NLAY * HD * NST;      // 196,608
    u16*   Vb  = (u16*)d_ws;                // bf16 residual stream [l][h][b]
    u16*   V2  = Vb + SZB;                  // bf16 pre-LN buffer
    float* PAR = (float*)(V2 + SZB);
    float* lamr = PAR,        * lami = PAR + PP;
    float* dtr  = PAR + 2*PP, * dti  = PAR + 3*PP;
    float* c2r  = PAR + 4*PP, * c2i  = PAR + 5*PP;
    u16* KA = (u16*)(PAR + 6 * PP);                  // 6*512*848 u16
    float* PO = PAR + 6 * PP + (NLAY * HD * NKA) / 2;
    float* xT = PO + BB * HD;                        // 784*64 fp32
    float* PO2 = xT + LSEQ * BB;                     // 16 * 32768 fp32 = 2 MB

    precompute_k<<<(NLAY * HD * NST + 255) / 256, 256, 0, stream>>>(
        ldt, lar, aim, cre, cim, lamr, lami, dtr, dti, c2r, c2i);
    kq_k<<<(NLAY * HD * 49) / 256, 256, 0, stream>>>(
        lamr, lami, dtr, dti, c2r, c2i, KA);
    xt_k<<<(LSEQ * BB) / 256, 256, 0, stream>>>(x, xT);
    encoder_k<<<(LPADROWS * HD * 8) / 256, 256, 0, stream>>>(xT, ew, eb, Vb);

    // layers 0..4: conv (Vb -> V2), LN (V2 -> Vb)
    for (int i = 0; i < NLAY - 1; i++) {
        conv_k<<<512 * NCH, 128, 0, stream>>>(
            Vb, V2, KA + (size_t)i * HD * NKA, Dp + i * HD);
        lnT_k<<<LSEQ, 512, 0, stream>>>(V2, Vb, lng + i * HD, lnb + i * HD);
    }
    // layer 5: conv, then fused LN5 + final LN in one pass
    conv_k<<<512 * NCH, 128, 0, stream>>>(
        Vb, V2, KA + (size_t)5 * HD * NKA, Dp + 5 * HD);
    lnT2s_k<<<LSEQ, 512, 0, stream>>>(V2, Vb, lng + 5 * HD, lnb + 5 * HD, fng, fnb);

    pool2_k<<<256, 256, 0, stream>>>(Vb, PO2);
    poolr_k<<<(HD * BB) / 256, 256, 0, stream>>>(PO2, PO);
    dec_k<<<(BB * 10 + 255) / 256, 256, 0, stream>>>(PO, dw, db, out);
}